// Round 14
// baseline (56.574 us; speedup 1.0000x reference)
//
#include <hip/hip_runtime.h>
#include <hip/hip_bf16.h>

// Problem constants (from reference): B=32, N=2048, M=16, K=32, H=in_sizes[2]
constexpr int Bc = 32;
constexpr int Nc = 2048;
constexpr int Mc = 16;
constexpr int Kc = 32;
constexpr int ROWc = 17;           // 17 floats per dgm row
constexpr int CH = 256;            // rows per staged chunk
constexpr int NCH = Nc / CH;       // 8 chunks per batch
constexpr int KQ = 8;              // k's per block (k-octet)
constexpr int NKQ = Kc / KQ;       // 4 k-octets
constexpr int NBLK = Bc * NKQ * NCH;   // 1024 blocks
constexpr unsigned MAGIC = 0x5EEDC0DEu;
constexpr float EPSc = 1e-7f;
constexpr float HALF_LN2 = 0.34657359028f;   // 0.5 * ln 2

// ---------------------------------------------------------------------------
// SINGLE-DISPATCH fusion of r13's k_T + k_scan.
// Phase 1 (1024 blocks x 256 thr, byte-identical math to r13, passed@0.5):
//   P[row][m][c] partials via RELAXED AGENT-SCOPE atomic stores (write-through
//   to coherence point -- no dirty cross-XCD L2 lines, unlike r9's disaster),
//   then ONE release flag-store per block (tid0 only: 1024 release fences
//   total, not 262144 threadfences).
// Phase 2 (block 0): poll all 1024 flags (relaxed agent loads + s_sleep),
//   acquire fence (invalidates local L1/L2 -> plain loads see fresh P),
//   then the cumsum + tanh re-projection with 256 threads (seg of 64 rows).
//   Finally reset flags to 0 so every replay is self-consistent
//   (poison 0xAA != MAGIC, reset 0 != MAGIC; output deterministic).
// ---------------------------------------------------------------------------
__global__ __launch_bounds__(256) void k_all(const float* __restrict__ dgm,
                                             const float* __restrict__ theta,
                                             const float* __restrict__ class_w,
                                             float* __restrict__ P,
                                             unsigned* __restrict__ flags,
                                             float* __restrict__ out,
                                             int H) {
    __shared__ float stage[CH * 20];   // 20480 B: [row][20], hom@0, coords@4..19
    __shared__ float red[4 * KQ * 17]; // 2176 B: phase1 reduce; phase2 seg totals

    int bid = blockIdx.x;
    int b   = bid >> 5;                // bid = b*32 + kq*8 + c
    int rem = bid & 31;
    int kq  = rem >> 3;
    int c   = rem & 7;
    int tid = threadIdx.x;
    int k8  = tid & 7;
    int rg  = tid >> 3;                // 0..31 rowgroups x 8 rows

    // ---- stage 256x17 floats (1088 float4, coalesced) into padded layout ----
    const float4* src4 = (const float4*)(dgm + ((size_t)b * Nc + c * CH) * ROWc);
    for (int i = tid; i < (CH * ROWc) / 4; i += 256) {
        float4 v = src4[i];
        unsigned g = 4u * i;
#pragma unroll
        for (int e = 0; e < 4; ++e) {
            unsigned ge  = g + e;
            unsigned row = ge / 17u;
            unsigned col = ge - row * 17u;
            float val = (e == 0) ? v.x : (e == 1) ? v.y : (e == 2) ? v.z : v.w;
            stage[row * 20 + (col == 0 ? 0u : col + 3u)] = val;
        }
    }

    // ---- per-thread theta^2 for its global k = kq*8 + k8 ----
    int kg = kq * KQ + k8;
    float th2[16];
    {
        const float4* t4 = (const float4*)theta;
#pragma unroll
        for (int q = 0; q < 4; ++q) {
            float4 tv = t4[kg * 4 + q];
            th2[4*q+0] = tv.x * tv.x; th2[4*q+1] = tv.y * tv.y;
            th2[4*q+2] = tv.z * tv.z; th2[4*q+3] = tv.w * tv.w;
        }
    }
    float cw0 = class_w[0];
    float cw1 = (H > 1) ? class_w[1] : cw0;

    __syncthreads();

    // ---- accumulate 8 rows for this (k8, rowgroup) ----
    float acc[16];
#pragma unroll
    for (int m = 0; m < 16; ++m) acc[m] = 0.0f;

#pragma unroll
    for (int j = 0; j < 8; ++j) {
        int row = rg * 8 + j;
        const float* rp = &stage[row * 20];
        float r0 = rp[0];
        float r[16];
        {   // aligned float4 LDS reads, broadcast across the 8 k-lanes
            float4* rv = (float4*)r;
            const float4* lp = (const float4*)(rp + 4);
            rv[0] = lp[0]; rv[1] = lp[1]; rv[2] = lp[2]; rv[3] = lp[3];
        }

        int h = (int)r0;               // trunc == astype(int32)
        h = max(0, min(h, H - 1));
        float wv = (H == 2) ? (h ? cw1 : cw0) : class_w[h];

        float za = 0.f, zb = 0.f, zc = 0.f, zd = 0.f;   // 4 indep chains
#pragma unroll
        for (int m = 0; m < 16; m += 4) {
            za = fmaf(r[m]   * r[m],   th2[m],   za);
            zb = fmaf(r[m+1] * r[m+1], th2[m+1], zb);
            zc = fmaf(r[m+2] * r[m+2], th2[m+2], zc);
            zd = fmaf(r[m+3] * r[m+3], th2[m+3], zd);
        }
        float zn2 = (za + zb) + (zc + zd);
        float rs  = rsqrtf(fmaxf(zn2, 1e-30f));
        float zn  = zn2 * rs;                       // ||z|| (0 if zn2==0)
        float s   = sqrtf(1.0f + zn2);
        float at2 = __log2f(zn + s);
        float coef = HALF_LN2 * at2 * rs * wv;      // exactly 0 for zero rows
#pragma unroll
        for (int m = 0; m < 16; ++m) acc[m] = fmaf(coef, r[m], acc[m]);
    }

    // ---- fold the 8 rowgroups within each wave (lane bits 3,4,5) ----
#pragma unroll
    for (int m = 0; m < 16; ++m) {
        acc[m] += __shfl_xor(acc[m], 8);
        acc[m] += __shfl_xor(acc[m], 16);
        acc[m] += __shfl_xor(acc[m], 32);
    }

    int w = tid >> 6;                  // wave 0..3
    if ((tid & 63) < 8) {              // lane == k8 for these lanes
#pragma unroll
        for (int m = 0; m < 16; ++m) red[w * (KQ * 17) + k8 * 17 + m] = acc[m];
    }
    __syncthreads();

    // ---- P partial store: relaxed agent-scope (write-through) ----
    if (tid < KQ * 16) {
        int kk = tid >> 4;             // 0..7
        int mm = tid & 15;
        float s = 0.0f;
#pragma unroll
        for (int w2 = 0; w2 < 4; ++w2) s += red[w2 * (KQ * 17) + kk * 17 + mm];
        float val = s * theta[kq * 128 + tid];
        size_t idx = (size_t)b * 4096 + (size_t)kq * 1024 + (size_t)kk * 128 + mm * 8 + c;
        __hip_atomic_store(&P[idx], val, __ATOMIC_RELAXED, __HIP_MEMORY_SCOPE_AGENT);
    }
    __syncthreads();                   // all P stores of this block issued+drained
    if (tid == 0) {                    // release: orders P stores before flag
        __hip_atomic_store(&flags[bid], MAGIC, __ATOMIC_RELEASE, __HIP_MEMORY_SCOPE_AGENT);
    }

    if (bid != 0) return;

    // ---------------- Phase 2: block 0 polls, then scans ----------------
    {
        int f0 = tid * 4;              // 256 threads x 4 flags = 1024
        for (;;) {
            bool ok = true;
#pragma unroll
            for (int j = 0; j < 4; ++j)
                ok = ok && (__hip_atomic_load(&flags[f0 + j], __ATOMIC_RELAXED,
                                              __HIP_MEMORY_SCOPE_AGENT) == MAGIC);
            if (ok) break;
            __builtin_amdgcn_s_sleep(1);
        }
        __builtin_amdgcn_fence(__ATOMIC_ACQUIRE, "agent");  // invalidate L1/L2
    }
    __syncthreads();

    // thread = (m = tid&15, seg = tid>>4); seg owns 64 consecutive rows
    int m   = tid & 15;
    int seg = tid >> 4;                // 0..15
    int r0  = seg * 64;

    // pass A: segment totals
    float tot = 0.0f;
    for (int j = 0; j < 64; ++j) {
        const float4* q = (const float4*)(P + (size_t)(r0 + j) * 128 + m * 8);
        float4 a = q[0], bq = q[1];
        tot += ((a.x + a.y) + (a.z + a.w)) + ((bq.x + bq.y) + (bq.z + bq.w));
    }
    red[seg * 16 + m] = tot;
    __syncthreads();
    float off = 0.0f;
    for (int s2 = 0; s2 < seg; ++s2) off += red[s2 * 16 + m];

    // pass B: running prefix + transform
    float run = off;
    for (int j = 0; j < 64; ++j) {
        int row = r0 + j;
        const float4* q = (const float4*)(P + (size_t)row * 128 + m * 8);
        float4 a = q[0], bq = q[1];
        run += ((a.x + a.y) + (a.z + a.w)) + ((bq.x + bq.y) + (bq.z + bq.w));
        float S = run;
        float sn2 = S * S;             // reduce over the 16 m-lanes
        sn2 += __shfl_xor(sn2, 1);
        sn2 += __shfl_xor(sn2, 2);
        sn2 += __shfl_xor(sn2, 4);
        sn2 += __shfl_xor(sn2, 8);
        float sn = sqrtf(sn2);
        float e  = __expf(2.0f * sn);  // tanh(sn) = 1 - 2/(e^{2sn}+1)
        float t  = 1.0f - 2.0f / (e + 1.0f);
        float cc = t / fmaxf(sn, EPSc);
        float sx2 = cc * cc * sn2;     // == sum(xd^2)
        float yd = 2.0f * cc * S / (1.0f - sx2);
        out[(size_t)row * Mc + m] = yd;
    }

    // reset flags so the next replay is self-consistent
    __syncthreads();
#pragma unroll
    for (int j = 0; j < 4; ++j)
        __hip_atomic_store(&flags[tid * 4 + j], 0u, __ATOMIC_RELAXED,
                           __HIP_MEMORY_SCOPE_AGENT);
}

// ---------------------------------------------------------------------------
extern "C" void kernel_launch(void* const* d_in, const int* in_sizes, int n_in,
                              void* d_out, int out_size, void* d_ws, size_t ws_size,
                              hipStream_t stream) {
    const float* dgm     = (const float*)d_in[0];   // (B, N, 17)
    const float* theta   = (const float*)d_in[1];   // (K, M)
    const float* class_w = (const float*)d_in[2];   // (H,)
    int H = in_sizes[2];

    float*    P     = (float*)d_ws;                 // 1024 x 128 floats = 512 KB
    unsigned* flags = (unsigned*)((char*)d_ws + (size_t)NBLK * 128 * sizeof(float));
    float*    out   = (float*)d_out;

    k_all<<<NBLK, 256, 0, stream>>>(dgm, theta, class_w, P, flags, out, H);
}

// Round 15
// 29.776 us; speedup vs baseline: 1.9000x; 1.9000x over previous
//
#include <hip/hip_runtime.h>
#include <hip/hip_bf16.h>

// Problem constants (from reference): B=32, N=2048, M=16, K=32, H=in_sizes[2]
constexpr int Bc = 32;
constexpr int Nc = 2048;
constexpr int Mc = 16;
constexpr int Kc = 32;
constexpr int ROWc = 17;           // 17 floats per dgm row
constexpr int CH = 256;            // rows per staged chunk
constexpr int NCH = Nc / CH;       // 8 chunks per batch
constexpr int KQ = 8;              // k's per block (k-octet)
constexpr int NKQ = Kc / KQ;       // 4 k-octets
constexpr float EPSc = 1e-7f;
constexpr float HALF_LN2 = 0.34657359028f;   // 0.5 * ln 2

// ---------------------------------------------------------------------------
// Kernel A (r13 winner + zero-chunk skip): 1024 blocks x 256 threads.
// Thread (k8 = tid&7, rg = tid>>3) accumulates its k over 8 broadcast rows.
// NEW: while staging, each thread tests its values for nonzero; a wave __any
// + 4-flag LDS OR (piggybacking on the existing barrier) yields block-uniform
// anynz. ~19% of blocks cover entirely-zero chunks (lengths ~ U[N/2,N]) and
// skip the whole transcendental pipeline, storing zero partials directly.
// Math (passed absmax<=0.5 since r10):
//   T[b,k,m] = th[k][m] * sum_n coef(n,k)*y[n,m],
//   coef = 0.5*asinh(||z||)/||z|| * w   (atanh(||x||) = asinh(||z||)/2);
//   zero rows contribute exactly 0.
// P layout: P[((b*32+kq*8+kk)*16+mm)*8 + c], chunk index contiguous.
// ---------------------------------------------------------------------------
__global__ __launch_bounds__(256) void k_T(const float* __restrict__ dgm,
                                           const float* __restrict__ theta,
                                           const float* __restrict__ class_w,
                                           float* __restrict__ P,
                                           int H) {
    __shared__ float stage[CH * 20];   // 20480 B: [row][20], hom@0, coords@4..19
    __shared__ float red[4 * KQ * 17]; // 2176 B: [wave][k8*17 + m] padded
    __shared__ int   nzf[4];           // per-wave nonzero flags

    int bid = blockIdx.x;
    int b   = bid >> 5;                // bid = b*32 + kq*8 + c
    int rem = bid & 31;
    int kq  = rem >> 3;
    int c   = rem & 7;
    int tid = threadIdx.x;
    int k8  = tid & 7;
    int rg  = tid >> 3;                // 0..31 rowgroups x 8 rows

    // ---- stage 256x17 floats (1088 float4, coalesced) + nonzero probe ----
    bool mynz = false;
    const float4* src4 = (const float4*)(dgm + ((size_t)b * Nc + c * CH) * ROWc);
    for (int i = tid; i < (CH * ROWc) / 4; i += 256) {
        float4 v = src4[i];
        mynz = mynz || (v.x != 0.0f) || (v.y != 0.0f) || (v.z != 0.0f) || (v.w != 0.0f);
        unsigned g = 4u * i;
#pragma unroll
        for (int e = 0; e < 4; ++e) {
            unsigned ge  = g + e;
            unsigned row = ge / 17u;
            unsigned col = ge - row * 17u;
            float val = (e == 0) ? v.x : (e == 1) ? v.y : (e == 2) ? v.z : v.w;
            stage[row * 20 + (col == 0 ? 0u : col + 3u)] = val;
        }
    }
    if ((tid & 63) == 0) nzf[tid >> 6] = 0;   // init before barrier
    // (init then set below; both before the same barrier, ordered per-wave)
    if (__any(mynz) && (tid & 63) == 0) nzf[tid >> 6] = 1;

    // ---- per-thread theta^2 for its global k = kq*8 + k8 ----
    int kg = kq * KQ + k8;
    float th2[16];
    {
        const float4* t4 = (const float4*)theta;
#pragma unroll
        for (int q = 0; q < 4; ++q) {
            float4 tv = t4[kg * 4 + q];
            th2[4*q+0] = tv.x * tv.x; th2[4*q+1] = tv.y * tv.y;
            th2[4*q+2] = tv.z * tv.z; th2[4*q+3] = tv.w * tv.w;
        }
    }
    float cw0 = class_w[0];
    float cw1 = (H > 1) ? class_w[1] : cw0;

    __syncthreads();

    bool anynz = (nzf[0] | nzf[1] | nzf[2] | nzf[3]) != 0;   // block-uniform

    if (anynz) {
        // ---- accumulate 8 rows for this (k8, rowgroup) ----
        float acc[16];
#pragma unroll
        for (int m = 0; m < 16; ++m) acc[m] = 0.0f;

#pragma unroll
        for (int j = 0; j < 8; ++j) {
            int row = rg * 8 + j;
            const float* rp = &stage[row * 20];
            float r0 = rp[0];
            float r[16];
            {   // aligned float4 LDS reads, broadcast across the 8 k-lanes
                float4* rv = (float4*)r;
                const float4* lp = (const float4*)(rp + 4);
                rv[0] = lp[0]; rv[1] = lp[1]; rv[2] = lp[2]; rv[3] = lp[3];
            }

            int h = (int)r0;               // trunc == astype(int32)
            h = max(0, min(h, H - 1));
            float wv = (H == 2) ? (h ? cw1 : cw0) : class_w[h];

            float za = 0.f, zb = 0.f, zc = 0.f, zd = 0.f;   // 4 indep chains
#pragma unroll
            for (int m = 0; m < 16; m += 4) {
                za = fmaf(r[m]   * r[m],   th2[m],   za);
                zb = fmaf(r[m+1] * r[m+1], th2[m+1], zb);
                zc = fmaf(r[m+2] * r[m+2], th2[m+2], zc);
                zd = fmaf(r[m+3] * r[m+3], th2[m+3], zd);
            }
            float zn2 = (za + zb) + (zc + zd);
            float rs  = rsqrtf(fmaxf(zn2, 1e-30f));
            float zn  = zn2 * rs;                       // ||z|| (0 if zn2==0)
            float s   = sqrtf(1.0f + zn2);
            float at2 = __log2f(zn + s);
            float coef = HALF_LN2 * at2 * rs * wv;      // exactly 0 for zero rows
#pragma unroll
            for (int m = 0; m < 16; ++m) acc[m] = fmaf(coef, r[m], acc[m]);
        }

        // ---- fold the 8 rowgroups within each wave (lane bits 3,4,5) ----
#pragma unroll
        for (int m = 0; m < 16; ++m) {
            acc[m] += __shfl_xor(acc[m], 8);
            acc[m] += __shfl_xor(acc[m], 16);
            acc[m] += __shfl_xor(acc[m], 32);
        }

        int w = tid >> 6;                  // wave 0..3
        if ((tid & 63) < 8) {              // lane == k8 for these lanes
#pragma unroll
            for (int m = 0; m < 16; ++m) red[w * (KQ * 17) + k8 * 17 + m] = acc[m];
        }
        __syncthreads();

        // ---- final: one (k8,m) pair per thread; apply theta; store partial ----
        if (tid < KQ * 16) {
            int kk = tid >> 4;             // 0..7
            int mm = tid & 15;
            float s = 0.0f;
#pragma unroll
            for (int w2 = 0; w2 < 4; ++w2) s += red[w2 * (KQ * 17) + kk * 17 + mm];
            float val = s * theta[kq * 128 + tid];      // theta[(kq*8+kk)*16+mm]
            P[((size_t)b * 4096 + (size_t)kq * 1024 + (size_t)(tid >> 4) * 128
               + (size_t)(tid & 15) * 8) + c] = val;
        }
    } else {
        // entire chunk is zero -> partials are exactly zero
        if (tid < KQ * 16) {
            P[((size_t)b * 4096 + (size_t)kq * 1024 + (size_t)(tid >> 4) * 128
               + (size_t)(tid & 15) * 8) + c] = 0.0f;
        }
    }
}

// ---------------------------------------------------------------------------
// Kernel B (unchanged from r12/r13): T[row][m] = sum_c P[row][m][c] via two
// aligned float4 loads; S = cumsum over the 1024 flattened rows;
// yd = 2*xd/(1-||xd||^2), xd = tanh(||S||)*S/max(||S||,eps).
// Single block, 1024 threads; thread = (m = tid&15, seg = tid>>4).
// ---------------------------------------------------------------------------
__global__ __launch_bounds__(1024) void k_scan(const float* __restrict__ P,
                                               float* __restrict__ out) {
    __shared__ float buf[2][64][Mc];

    int tid = threadIdx.x;
    int m   = tid & 15;
    int seg = tid >> 4;            // 0..63, 16 rows each -> 1024 rows

    float p[16];
    float run = 0.0f;
#pragma unroll
    for (int j = 0; j < 16; ++j) {
        int row = seg * 16 + j;    // = b*32 + k
        const float4* q = (const float4*)(P + (size_t)row * 128 + m * 8);
        float4 a = q[0];
        float4 bq = q[1];
        run += ((a.x + a.y) + (a.z + a.w)) + ((bq.x + bq.y) + (bq.z + bq.w));
        p[j] = run;
    }

    buf[0][seg][m] = run;
    __syncthreads();
    int src = 0;
#pragma unroll
    for (int d = 1; d < 64; d <<= 1) {
        float v = buf[src][seg][m];
        if (seg >= d) v += buf[src][seg - d][m];
        buf[src ^ 1][seg][m] = v;
        __syncthreads();
        src ^= 1;
    }
    float off = (seg > 0) ? buf[src][seg - 1][m] : 0.0f;

#pragma unroll
    for (int j = 0; j < 16; ++j) {
        float S = off + p[j];
        float sn2 = S * S;
        sn2 += __shfl_xor(sn2, 1);
        sn2 += __shfl_xor(sn2, 2);
        sn2 += __shfl_xor(sn2, 4);
        sn2 += __shfl_xor(sn2, 8);
        float sn = sqrtf(sn2);
        // tanh(sn) = 1 - 2/(e^{2 sn}+1)
        float e  = __expf(2.0f * sn);
        float t  = 1.0f - 2.0f / (e + 1.0f);
        float cc = t / fmaxf(sn, EPSc);
        float sx2 = cc * cc * sn2;             // == sum(xd^2)
        float yd = 2.0f * cc * S / (1.0f - sx2);
        out[(size_t)(seg * 16 + j) * Mc + m] = yd;
    }
}

// ---------------------------------------------------------------------------
extern "C" void kernel_launch(void* const* d_in, const int* in_sizes, int n_in,
                              void* d_out, int out_size, void* d_ws, size_t ws_size,
                              hipStream_t stream) {
    const float* dgm     = (const float*)d_in[0];   // (B, N, 17)
    const float* theta   = (const float*)d_in[1];   // (K, M)
    const float* class_w = (const float*)d_in[2];   // (H,)
    int H = in_sizes[2];

    float* P   = (float*)d_ws;                      // 1024 x 128 floats = 512 KB
    float* out = (float*)d_out;

    k_T<<<Bc * NKQ * NCH, 256, 0, stream>>>(dgm, theta, class_w, P, H);
    k_scan<<<1, 1024, 0, stream>>>(P, out);
}